// Round 1
// baseline (409.623 us; speedup 1.0000x reference)
//
#include <hip/hip_runtime.h>
#include <hip/hip_bf16.h>
#include <math.h>

#define SEQ_LEN 128
#define BATCH   32
#define T       32
#define TT      (T*T)     // 1024
#define TTT     (T*T*T)   // 32768
#define START   30
#define END     31

// ---------------------------------------------------------------------------
// Kernel 1: tg_energy gather. 4096 (s,b) pairs, one thread each.
// ws[0..15] <- per-block partial sums (written unconditionally, no init needed)
// ---------------------------------------------------------------------------
__global__ __launch_bounds__(256) void tg_kernel(const float* __restrict__ scores,
                                                 const int*   __restrict__ target,
                                                 const int*   __restrict__ mask,
                                                 float*       __restrict__ ws) {
    int idx = blockIdx.x * 256 + threadIdx.x;   // idx = s*BATCH + b, 0..4095
    float v = 0.0f;
    if (mask[idx] != 0) {
        v = scores[(size_t)idx * TTT + target[idx]];
    }
    // wave(64) reduce
    #pragma unroll
    for (int off = 32; off > 0; off >>= 1)
        v += __shfl_down(v, off, 64);
    __shared__ float partial[4];
    int wave = threadIdx.x >> 6;
    int lane = threadIdx.x & 63;
    if (lane == 0) partial[wave] = v;
    __syncthreads();
    if (threadIdx.x == 0)
        ws[blockIdx.x] = partial[0] + partial[1] + partial[2] + partial[3];
}

// ---------------------------------------------------------------------------
// Kernel 2: the CRF scan. One block per batch, 1024 threads, thread = (j,k).
// new_part[j,k] = LSE_i( scores[t,b,i,j,k] + part[i,j] )
// ws[16+b] <- final partition[b, END, END]
// ---------------------------------------------------------------------------
__global__ __launch_bounds__(1024) void scan_kernel(const float* __restrict__ scores,
                                                    const int*   __restrict__ mask,
                                                    float*       __restrict__ ws) {
    const int b   = blockIdx.x;
    const int tid = threadIdx.x;
    const int j   = tid >> 5;     // output row (middle index of this step)
    // (k = tid & 31 is implicit in the contiguous addressing)

    __shared__ float pA[TT];
    __shared__ float pB[TT];

    // init: part0[i,jj] = scores[0,b,START,START,i] + scores[1,b,START,i,jj]
    {
        int i  = tid >> 5;
        int jj = tid & 31;
        float p1 = scores[((size_t)(0*BATCH + b)*T + START)*TT + START*T + i];
        float s1 = scores[((size_t)(1*BATCH + b)*T + START)*TT + i*T + jj];
        pA[tid] = p1 + s1;
    }
    __syncthreads();

    float* cur = pA;
    float* nxt = pB;

    for (int t = 2; t < SEQ_LEN; ++t) {
        const float* __restrict__ sp = scores + (size_t)(t*BATCH + b)*TTT + tid;

        float buf[T];
        #pragma unroll
        for (int i = 0; i < T; ++i) buf[i] = sp[(size_t)i * TT];   // coalesced across tid
        #pragma unroll
        for (int i = 0; i < T; ++i) buf[i] += cur[i*T + j];        // LDS broadcast

        float m = buf[0];
        #pragma unroll
        for (int i = 1; i < T; ++i) m = fmaxf(m, buf[i]);
        float ssum = 0.0f;
        #pragma unroll
        for (int i = 0; i < T; ++i) ssum += __expf(buf[i] - m);

        float newv = m + __logf(ssum);
        if (mask[t*BATCH + b] == 0) newv = cur[tid];   // keep old partition if masked

        nxt[tid] = newv;          // writes go to the other buffer: no race with reads
        __syncthreads();          // one barrier per step
        float* tmp = cur; cur = nxt; nxt = tmp;
    }

    if (tid == 0) ws[16 + b] = cur[END*T + END];
}

// ---------------------------------------------------------------------------
// Kernel 3: deterministic finalize. out = (z - tg_energy) / BATCH
// ---------------------------------------------------------------------------
__global__ void finalize_kernel(const float* __restrict__ ws, float* __restrict__ out) {
    if (threadIdx.x == 0) {
        float tg = 0.0f, z = 0.0f;
        #pragma unroll
        for (int i = 0; i < 16; ++i) tg += ws[i];
        #pragma unroll
        for (int i = 0; i < 32; ++i) z += ws[16 + i];
        out[0] = (z - tg) / (float)BATCH;
    }
}

extern "C" void kernel_launch(void* const* d_in, const int* in_sizes, int n_in,
                              void* d_out, int out_size, void* d_ws, size_t ws_size,
                              hipStream_t stream) {
    const float* scores = (const float*)d_in[0];
    const int*   target = (const int*)d_in[1];
    const int*   mask   = (const int*)d_in[2];
    float* out = (float*)d_out;
    float* ws  = (float*)d_ws;

    tg_kernel<<<16, 256, 0, stream>>>(scores, target, mask, ws);
    scan_kernel<<<BATCH, 1024, 0, stream>>>(scores, mask, ws);
    finalize_kernel<<<1, 64, 0, stream>>>(ws, out);
}

// Round 2
// 278.507 us; speedup vs baseline: 1.4708x; 1.4708x over previous
//
#include <hip/hip_runtime.h>
#include <hip/hip_bf16.h>
#include <math.h>

#define SEQ_LEN 128
#define BATCH   32
#define T       32
#define TT      (T*T)     // 1024
#define TTT     (T*T*T)   // 32768
#define START   30
#define END     31
#define NGB     8         // blocks per batch
#define JPB     4         // output rows (j) per block

typedef unsigned long long u64;

// ---- packed (tag, value) helpers: one 64-bit word is self-consistent ----
__device__ __forceinline__ u64 pt_pack(int tag, float v) {
    union { float f; unsigned int u; } c; c.f = v;
    return ((u64)(unsigned int)tag << 32) | (u64)c.u;
}
__device__ __forceinline__ float pt_val(u64 w) {
    union { unsigned int u; float f; } c; c.u = (unsigned int)w; return c.f;
}
__device__ __forceinline__ int pt_tag(u64 w) { return (int)(w >> 32); }

__device__ __forceinline__ u64 ald64(const u64* p) {
    return __hip_atomic_load(p, __ATOMIC_RELAXED, __HIP_MEMORY_SCOPE_AGENT);
}
__device__ __forceinline__ void ast64(u64* p, u64 v) {
    __hip_atomic_store(p, v, __ATOMIC_RELAXED, __HIP_MEMORY_SCOPE_AGENT);
}

// ---------------------------------------------------------------------------
// Kernel 1: tg_energy gather. ws[0..15] <- per-block partial sums.
// ---------------------------------------------------------------------------
__global__ __launch_bounds__(256) void tg_kernel(const float* __restrict__ scores,
                                                 const int*   __restrict__ target,
                                                 const int*   __restrict__ mask,
                                                 float*       __restrict__ ws) {
    int idx = blockIdx.x * 256 + threadIdx.x;   // idx = s*BATCH + b
    float v = 0.0f;
    if (mask[idx] != 0) {
        v = scores[(size_t)idx * TTT + target[idx]];
    }
    #pragma unroll
    for (int off = 32; off > 0; off >>= 1)
        v += __shfl_down(v, off, 64);
    __shared__ float partial[4];
    int wave = threadIdx.x >> 6;
    int lane = threadIdx.x & 63;
    if (lane == 0) partial[wave] = v;
    __syncthreads();
    if (threadIdx.x == 0)
        ws[blockIdx.x] = partial[0] + partial[1] + partial[2] + partial[3];
}

// ---------------------------------------------------------------------------
// Kernel 2: init. Writes initial partition (after reference step 1) into
// pt64 buf1 with tag=1, and clears buf0 tags (stale-tag safety across replays).
// pt64 layout: [b][buf][j*32+i]  (consumed orientation part[i][j] at [j*32+i])
// ---------------------------------------------------------------------------
__global__ __launch_bounds__(1024) void init_kernel(const float* __restrict__ scores,
                                                    u64* __restrict__ pt64) {
    int b = blockIdx.x, tid = threadIdx.x;
    int x = tid >> 5, y = tid & 31;
    float p1 = scores[(size_t)(0*BATCH + b)*TTT + START*TT + START*T + x];
    float s1 = scores[(size_t)(1*BATCH + b)*TTT + START*TT + x*T + y];
    u64* base = pt64 + (size_t)b * 2 * TT;
    base[TT + y*T + x] = pt_pack(1, p1 + s1);   // buf1: initial partition, tag 1
    base[tid]          = 0ULL;                   // buf0: tag 0
}

// ---------------------------------------------------------------------------
// Kernel 3: distributed scan. 256 blocks = 32 batches x 8 groups.
// Block (b,g) computes output rows j in [4g, 4g+4) each step.
// Wave 0 = sync wave (poll/publish, no score loads).
// Waves 1..15 = compute (depth-4 register prefetch, raw barriers only).
// ---------------------------------------------------------------------------
__global__ __launch_bounds__(1024, 4) void scan_kernel(const float* __restrict__ scores,
                                                       const int*   __restrict__ maskI,
                                                       u64*         __restrict__ pt64) {
    const int bid = blockIdx.x;
    const int b   = bid & (BATCH - 1);
    const int g   = bid >> 5;
    const int tid = threadIdx.x;

    __shared__ float smem[128 * 32];  // swizzled score tile, [o][sw]
    __shared__ float pl[128];         // part columns: pl[jj*32+i] = p[i][4g+jj]
    __shared__ float plT[128];        // masked-step pass-through values
    __shared__ float res[128];        // per-output results

    u64* ptbase = pt64 + (size_t)b * 2 * TT;

    const bool is_sync = (tid < 64);
    const int  lane = tid & 63;
    const int  ct   = tid - 64;       // compute-thread index (valid when !is_sync)

    int off1 = 0, off2 = 0;
    bool has2 = false;
    if (!is_sync) {
        off1 = (ct >> 5) * TT + (ct & 31) * 4;
        if (ct < 64) { has2 = true; off2 = ((960 + ct) >> 5) * TT + ((960 + ct) & 31) * 4; }
    }

    // reduce-phase constants: output o = tid>>3, 8 reducer lanes per output
    const int o   = tid >> 3, s8 = tid & 7;
    const int jj  = o >> 5, qo = o & 3;
    const int co  = (jj << 3) | ((o >> 2) & 7);
    const int swb = co + 2 * qo;

    // prologue: prefetch score tiles for t = 2..5
    float4 a0, a1, a2, a3, e0, e1, e2, e3;
    if (!is_sync) {
        const float* sb;
        sb = scores + (size_t)(2*BATCH + b)*TTT;
        a0 = *(const float4*)(sb + off1); if (has2) e0 = *(const float4*)(sb + off2);
        sb = scores + (size_t)(3*BATCH + b)*TTT;
        a1 = *(const float4*)(sb + off1); if (has2) e1 = *(const float4*)(sb + off2);
        sb = scores + (size_t)(4*BATCH + b)*TTT;
        a2 = *(const float4*)(sb + off1); if (has2) e2 = *(const float4*)(sb + off2);
        sb = scores + (size_t)(5*BATCH + b)*TTT;
        a3 = *(const float4*)(sb + off1); if (has2) e3 = *(const float4*)(sb + off2);
    }

    auto step = [&](int t, float4& a, float4& e) {
        const u64* ptp = ptbase + ((t - 1) & 1) * TT;   // prev partition
        u64*       ptn = ptbase + (t & 1) * TT;         // next partition
        const bool maskv = (maskI[t * BATCH + b] != 0);

        // ---------------- phase A ----------------
        if (is_sync) {
            const int tagw = t - 1;
            const u64* src = ptp + 128 * g + lane;
            u64 w0 = 0, w1 = 0; bool d0 = false, d1 = false;
            while (true) {
                if (!d0) { w0 = ald64(src);      d0 = (pt_tag(w0) == tagw); }
                if (!d1) { w1 = ald64(src + 64); d1 = (pt_tag(w1) == tagw); }
                if (__all(d0 && d1)) break;
            }
            pl[lane]      = pt_val(w0);
            pl[lane + 64] = pt_val(w1);
            if (!maskv) {
                int o0 = lane, o1 = lane + 64;
                const u64* q0 = ptp + (o0 & 31) * T + JPB * g + (o0 >> 5);
                const u64* q1 = ptp + (o1 & 31) * T + JPB * g + (o1 >> 5);
                u64 x0 = 0, x1 = 0; bool f0 = false, f1 = false;
                while (true) {
                    if (!f0) { x0 = ald64(q0); f0 = (pt_tag(x0) == tagw); }
                    if (!f1) { x1 = ald64(q1); f1 = (pt_tag(x1) == tagw); }
                    if (__all(f0 && f1)) break;
                }
                plT[lane]      = pt_val(x0);
                plT[lane + 64] = pt_val(x1);
            }
        } else {
            // scatter current score tile into swizzled LDS (conflict-free)
            {
                int i = ct >> 5, c = ct & 31;
                int ob = ((c >> 3) << 5) | ((c & 7) << 2);
                smem[(ob + 0) * 32 + ((i + c + 0) & 31)] = a.x;
                smem[(ob + 1) * 32 + ((i + c + 2) & 31)] = a.y;
                smem[(ob + 2) * 32 + ((i + c + 4) & 31)] = a.z;
                smem[(ob + 3) * 32 + ((i + c + 6) & 31)] = a.w;
            }
            if (has2) {
                int sl = 960 + ct;
                int i = sl >> 5, c = sl & 31;
                int ob = ((c >> 3) << 5) | ((c & 7) << 2);
                smem[(ob + 0) * 32 + ((i + c + 0) & 31)] = e.x;
                smem[(ob + 1) * 32 + ((i + c + 2) & 31)] = e.y;
                smem[(ob + 2) * 32 + ((i + c + 4) & 31)] = e.z;
                smem[(ob + 3) * 32 + ((i + c + 6) & 31)] = e.w;
            }
            // issue prefetch for step t+4 (stays in flight across raw barriers)
            if (t + 4 < SEQ_LEN) {
                const float* sb2 = scores + (size_t)((t + 4) * BATCH + b) * TTT;
                a = *(const float4*)(sb2 + off1);
                if (has2) e = *(const float4*)(sb2 + off2);
            }
        }
        __builtin_amdgcn_sched_barrier(0);
        asm volatile("s_waitcnt lgkmcnt(0)" ::: "memory");
        __builtin_amdgcn_sched_barrier(0);
        __builtin_amdgcn_s_barrier();
        __builtin_amdgcn_sched_barrier(0);

        // ---------------- phase B: reduce (all 1024 threads) ----------------
        {
            int i0 = s8 * 4;
            float v0 = smem[(o << 5) + ((i0 + 0 + swb) & 31)] + pl[(jj << 5) + i0 + 0];
            float v1 = smem[(o << 5) + ((i0 + 1 + swb) & 31)] + pl[(jj << 5) + i0 + 1];
            float v2 = smem[(o << 5) + ((i0 + 2 + swb) & 31)] + pl[(jj << 5) + i0 + 2];
            float v3 = smem[(o << 5) + ((i0 + 3 + swb) & 31)] + pl[(jj << 5) + i0 + 3];
            float m = fmaxf(fmaxf(v0, v1), fmaxf(v2, v3));
            m = fmaxf(m, __shfl_xor(m, 1, 8));
            m = fmaxf(m, __shfl_xor(m, 2, 8));
            m = fmaxf(m, __shfl_xor(m, 4, 8));
            float p = __expf(v0 - m) + __expf(v1 - m) + __expf(v2 - m) + __expf(v3 - m);
            p += __shfl_xor(p, 1, 8);
            p += __shfl_xor(p, 2, 8);
            p += __shfl_xor(p, 4, 8);
            if (s8 == 0) {
                float val;
                if (maskv) val = m + __logf(p);
                else       val = plT[o];
                res[o] = val;
            }
        }
        __builtin_amdgcn_sched_barrier(0);
        asm volatile("s_waitcnt lgkmcnt(0)" ::: "memory");
        __builtin_amdgcn_sched_barrier(0);
        __builtin_amdgcn_s_barrier();
        __builtin_amdgcn_sched_barrier(0);

        // ---------------- phase C: publish (wave 0 only) ----------------
        if (is_sync) {
            float r0 = res[lane], r1 = res[lane + 64];
            int o0 = lane, o1 = lane + 64;
            ast64(ptn + (o0 & 31) * T + JPB * g + (o0 >> 5), pt_pack(t, r0));
            ast64(ptn + (o1 & 31) * T + JPB * g + (o1 >> 5), pt_pack(t, r1));
        }
    };

    for (int t = 2; t < SEQ_LEN; t += 4) {
        step(t, a0, e0);
        if (t + 1 < SEQ_LEN) step(t + 1, a1, e1);
        if (t + 2 < SEQ_LEN) step(t + 2, a2, e2);
        if (t + 3 < SEQ_LEN) step(t + 3, a3, e3);
    }
}

// ---------------------------------------------------------------------------
// Kernel 4: finalize. out = (z - tg_energy) / BATCH
// ---------------------------------------------------------------------------
__global__ void finalize64(const float* __restrict__ ws, const u64* __restrict__ pt64,
                           float* __restrict__ out) {
    if (threadIdx.x == 0) {
        float tg = 0.f, z = 0.f;
        #pragma unroll
        for (int i = 0; i < 16; ++i) tg += ws[i];
        for (int b = 0; b < BATCH; ++b)
            z += pt_val(pt64[(size_t)(b * 2 + 1) * TT + END * T + END]);
        out[0] = (z - tg) / (float)BATCH;
    }
}

// ---------------------------------------------------------------------------
// Fallback path (small ws): round-1 single-block-per-batch scan.
// ---------------------------------------------------------------------------
__global__ __launch_bounds__(1024) void scan_simple(const float* __restrict__ scores,
                                                    const int*   __restrict__ mask,
                                                    float*       __restrict__ ws) {
    const int b   = blockIdx.x;
    const int tid = threadIdx.x;
    const int j   = tid >> 5;

    __shared__ float pA[TT];
    __shared__ float pB[TT];
    {
        int i  = tid >> 5;
        int jjy = tid & 31;
        float p1 = scores[((size_t)(0*BATCH + b)*T + START)*TT + START*T + i];
        float s1 = scores[((size_t)(1*BATCH + b)*T + START)*TT + i*T + jjy];
        pA[tid] = p1 + s1;
    }
    __syncthreads();
    float* cur = pA;
    float* nxt = pB;
    for (int t = 2; t < SEQ_LEN; ++t) {
        const float* __restrict__ sp = scores + (size_t)(t*BATCH + b)*TTT + tid;
        float buf[T];
        #pragma unroll
        for (int i = 0; i < T; ++i) buf[i] = sp[(size_t)i * TT];
        #pragma unroll
        for (int i = 0; i < T; ++i) buf[i] += cur[i*T + j];
        float m = buf[0];
        #pragma unroll
        for (int i = 1; i < T; ++i) m = fmaxf(m, buf[i]);
        float ssum = 0.0f;
        #pragma unroll
        for (int i = 0; i < T; ++i) ssum += __expf(buf[i] - m);
        float newv = m + __logf(ssum);
        if (mask[t*BATCH + b] == 0) newv = cur[tid];
        nxt[tid] = newv;
        __syncthreads();
        float* tmp = cur; cur = nxt; nxt = tmp;
    }
    if (tid == 0) ws[16 + b] = cur[END*T + END];
}

__global__ void finalize_simple(const float* __restrict__ ws, float* __restrict__ out) {
    if (threadIdx.x == 0) {
        float tg = 0.0f, z = 0.0f;
        #pragma unroll
        for (int i = 0; i < 16; ++i) tg += ws[i];
        #pragma unroll
        for (int i = 0; i < 32; ++i) z += ws[16 + i];
        out[0] = (z - tg) / (float)BATCH;
    }
}

extern "C" void kernel_launch(void* const* d_in, const int* in_sizes, int n_in,
                              void* d_out, int out_size, void* d_ws, size_t ws_size,
                              hipStream_t stream) {
    const float* scores = (const float*)d_in[0];
    const int*   target = (const int*)d_in[1];
    const int*   mask   = (const int*)d_in[2];
    float* out = (float*)d_out;
    float* ws  = (float*)d_ws;
    u64*   pt64 = (u64*)((char*)d_ws + 2048);
    const size_t need = 2048 + (size_t)2 * BATCH * TT * sizeof(u64);

    tg_kernel<<<16, 256, 0, stream>>>(scores, target, mask, ws);
    if (ws_size >= need) {
        init_kernel<<<BATCH, 1024, 0, stream>>>(scores, pt64);
        scan_kernel<<<BATCH * NGB, 1024, 0, stream>>>(scores, mask, pt64);
        finalize64<<<1, 64, 0, stream>>>(ws, pt64, out);
    } else {
        scan_simple<<<BATCH, 1024, 0, stream>>>(scores, mask, ws);
        finalize_simple<<<1, 64, 0, stream>>>(ws, out);
    }
}